// Round 3
// baseline (65779.089 us; speedup 1.0000x reference)
//
#include <hip/hip_runtime.h>
#include <math.h>

#define BB 32
#define SS 64
#define HH 256
#define NT 1024

// ws float offsets
//  [0]        weight packs: 8 gate mats x 4 slices x 16384 f4 + W1/W2 packs (2x4x4096 f4)
//  SH_OFF     per-batch shared: h1cw[64][256], h2cw[64][256], h1buf[256], h2buf[256],
//             dh1buf[256], dh2buf[256], partbuf[256]   (SHB floats each)
//  X1_OFF     per-block private X1 [64][256]
//  FLAGS_OFF  32 batches x 32 u32 flags
#define SH_OFF    2228224
#define SHB       34048
#define X1_OFF    3317760
#define FLAGS_OFF 5414912

__device__ __forceinline__ float sigmf(float x){ return 1.f/(1.f+expf(-x)); }
__device__ __forceinline__ float dot4(float4 a, float4 b){
  return fmaf(a.x,b.x,fmaf(a.y,b.y,fmaf(a.z,b.z,a.w*b.w)));
}
__device__ __forceinline__ void fst(unsigned* p, unsigned v){
  __hip_atomic_store(p, v, __ATOMIC_RELEASE, __HIP_MEMORY_SCOPE_AGENT);
}
__device__ __forceinline__ unsigned fld(unsigned* p){
  return __hip_atomic_load(p, __ATOMIC_ACQUIRE, __HIP_MEMORY_SCOPE_AGENT);
}
__device__ __forceinline__ void srel(float* p, float v){
  __hip_atomic_store(p, v, __ATOMIC_RELAXED, __HIP_MEMORY_SCOPE_AGENT);
}
__device__ __forceinline__ float lrel(const float* p){
  return __hip_atomic_load((float*)p, __ATOMIC_RELAXED, __HIP_MEMORY_SCOPE_AGENT);
}

// Zero the flag words (stale seqnos from previous call would deadlock/corrupt).
__global__ void zflags_k(float* ws){
  unsigned* f = (unsigned*)(ws + FLAGS_OFF);
  f[threadIdx.x] = 0u;   // 1024 = 32 batches x 32 words
}

// Pack weights into per-slice k-major float4 layout.
// Gate mats: dst4[(m*4+q)*16384 + kq*256 + r] = src_m[rowg][4kq..4kq+3],
//   rowg = (r>>6)*256 + q*64 + (r&63)  (r = gate*64 + jlocal)
// W1/W2: dst4[524288 + m2*16384 + q*4096 + kq*64 + jl] = src[(q*64+jl)][4kq..]
__global__ void pack_k(const float* __restrict__ e0ih, const float* __restrict__ e0hh,
                       const float* __restrict__ e1ih, const float* __restrict__ e1hh,
                       const float* __restrict__ d0ih, const float* __restrict__ d0hh,
                       const float* __restrict__ d1ih, const float* __restrict__ d1hh,
                       const float* __restrict__ W1,  const float* __restrict__ W2,
                       float* __restrict__ ws){
  const float* mats[8] = {e0ih,e0hh,e1ih,e1hh,d0ih,d0hh,d1ih,d1hh};
  float4* dst = (float4*)ws;
  int gid = blockIdx.x*256 + threadIdx.x;
  if (gid < 524288){
    int pack = gid >> 14, rem = gid & 16383;
    int m = pack >> 2, q = pack & 3;
    int kq = rem >> 8, r = rem & 255;
    int rowg = ((r>>6)<<8) + (q<<6) + (r&63);
    dst[gid] = *(const float4*)&mats[m][(size_t)rowg*256 + kq*4];
  } else {
    int g2 = gid - 524288;
    int m2 = g2 >> 14, rem = g2 & 16383;
    int q = rem >> 12, r2 = rem & 4095;
    int kq = r2 >> 6, jl = r2 & 63;
    const float* src = m2 ? W2 : W1;
    dst[524288 + m2*16384 + q*4096 + kq*64 + jl] =
      *(const float4*)&src[(size_t)(q*64+jl)*256 + kq*4];
  }
}

__global__ void __launch_bounds__(NT) ptrnet_k(
    const float* __restrict__ inputs, const float* __restrict__ W_emb,
    const float* __restrict__ b_emb,
    const float* __restrict__ b_e0, const float* __restrict__ b_e1,
    const float* __restrict__ b_d0, const float* __restrict__ b_d1,
    const float* __restrict__ vv,
    float* __restrict__ ws, float* __restrict__ out) {
  const int b = blockIdx.x >> 2;     // batch
  const int q = blockIdx.x & 3;      // slice (owns h-cols [64q,64q+64))
  const int tid = threadIdx.x;

  const float4* ws4 = (const float4*)ws;
  const float4* We0ih = ws4 + (0*4+q)*16384;
  const float4* We0hh = ws4 + (1*4+q)*16384;
  const float4* We1ih = ws4 + (2*4+q)*16384;
  const float4* We1hh = ws4 + (3*4+q)*16384;
  const float4* Wd0ih = ws4 + (4*4+q)*16384;
  const float4* Wd0hh = ws4 + (5*4+q)*16384;
  const float4* Wd1ih = ws4 + (6*4+q)*16384;
  const float4* Wd1hh = ws4 + (7*4+q)*16384;
  const float4* W1p = ws4 + 524288 + q*4096;
  const float4* W2p = ws4 + 524288 + 16384 + q*4096;

  float* shb   = ws + SH_OFF + (size_t)b*SHB;
  float* h1cw  = shb;            // [64][256] shared h1 cache
  float* h2cw  = shb + 16384;    // [64][256] shared h2 cache (= enc_out)
  float* h1buf = shb + 32768;    // [4][64] exchange
  float* h2buf = h1buf + 256;
  float* dh1buf= h2buf + 256;
  float* dh2buf= dh1buf + 256;
  float* partbuf=dh2buf + 256;   // [4][64] score partials
  unsigned* flags = ((unsigned*)(ws + FLAGS_OFF)) + b*32;
  // words: [0..3] enc-h1, [4..7] enc-h2, [8..11] dec-h1, [12..15] dec-h2,
  //        [16..19] partials, [20] idx flag, [21] idx value, [24..27] update handshake
  float* X1 = ws + X1_OFF + (size_t)blockIdx.x * 16384;  // [64][256 own gate rows]

  __shared__ float preE[SS][HH];   // pre-tanh embeddings (full)
  __shared__ float c1c[SS][64];    // own c slices per t
  __shared__ float c2c[SS][64];
  __shared__ float eW1s[SS][64];   // enc_out @ W1^T, own cols
  __shared__ float gbuf[1024];     // gate partial-reduce / staging (unioned)
  __shared__ float h1f[HH], h2f[HH], dh1f[HH], dh2f[HH], dins[HH], embt[HH];
  __shared__ float dc1s[64], dc2s[64], a2s[64];
  __shared__ int msk[SS];
  __shared__ int seli;

  // ---- phase 0: embed (pre-tanh) + init
  for (int i = tid; i < SS*HH; i += NT){
    int t = i >> 8, j = i & 255;
    const float* xr = inputs + ((size_t)b*SS + t)*8;
    float acc = b_emb[j];
#pragma unroll
    for (int d = 0; d < 8; ++d) acc = fmaf(xr[d], W_emb[j*8+d], acc);
    preE[t][j] = acc;
  }
  if (tid < HH){ h1f[tid] = 0.f; h2f[tid] = 0.f; }
  if (tid < SS) msk[tid] = 0;
  __syncthreads();

  // ---- phase 1: X1[t][own 256 gate rows] = b_e0 + tanh(preE[t]) @ Wih_e0^T
  // GEMM-tiled (4 t per tile) so the weight slice is re-read 16x not 64x.
  for (int tile = 0; tile < 16; ++tile){
    { int tt = tid >> 8, j = tid & 255; gbuf[tid] = tanhf(preE[tile*4+tt][j]); }
    __syncthreads();
    { int row = tid >> 2, c = tid & 3;
      float a0=0.f,a1=0.f,a2v=0.f,a3=0.f;
#pragma unroll
      for (int i = 0; i < 16; ++i){
        float4 w = We0ih[(c*16+i)*256 + row];
        a0  += dot4(w, *(const float4*)&gbuf[  0 + (c*16+i)*4]);
        a1  += dot4(w, *(const float4*)&gbuf[256 + (c*16+i)*4]);
        a2v += dot4(w, *(const float4*)&gbuf[512 + (c*16+i)*4]);
        a3  += dot4(w, *(const float4*)&gbuf[768 + (c*16+i)*4]);
      }
      a0 += __shfl_xor(a0,1);  a0 += __shfl_xor(a0,2);
      a1 += __shfl_xor(a1,1);  a1 += __shfl_xor(a1,2);
      a2v+= __shfl_xor(a2v,1); a2v+= __shfl_xor(a2v,2);
      a3 += __shfl_xor(a3,1);  a3 += __shfl_xor(a3,2);
      if (c == 0){
        float bg = b_e0[((row>>6)<<8) + (q<<6) + (row&63)];
        X1[(tile*4+0)*256 + row] = bg + a0;
        X1[(tile*4+1)*256 + row] = bg + a1;
        X1[(tile*4+2)*256 + row] = bg + a2v;
        X1[(tile*4+3)*256 + row] = bg + a3;
      }
    }
    __syncthreads();
  }

  int tauCnt = 1;

  // ---- encoder from t0 (incremental restart; caches persist in LDS/ws)
  auto encode_from = [&](int t0){
    if (tid < HH){
      float v1 = 0.f, v2 = 0.f;
      if (t0 > 0){ v1 = lrel(&h1cw[(t0-1)*256 + tid]); v2 = lrel(&h2cw[(t0-1)*256 + tid]); }
      h1f[tid] = v1; h2f[tid] = v2;
    }
    __syncthreads();
    for (int t = t0; t < SS; ++t){
      // layer1: own 256 gate rows, k-split 4
      { int row = tid & 255, c = tid >> 8;
        float acc = 0.f;
#pragma unroll
        for (int i = 0; i < 16; ++i){
          float4 w = We0hh[(c*16+i)*256 + row];
          acc += dot4(w, *(const float4*)&h1f[(c*16+i)*4]);
        }
        gbuf[c*256+row] = (c==0) ? acc + X1[t*256+row] : acc;
      }
      __syncthreads();
      if (tid < 64){
        int j = tid;
        float Gi = gbuf[    j]+gbuf[256+    j]+gbuf[512+    j]+gbuf[768+    j];
        float Gf = gbuf[ 64+j]+gbuf[256+ 64+j]+gbuf[512+ 64+j]+gbuf[768+ 64+j];
        float Gg = gbuf[128+j]+gbuf[256+128+j]+gbuf[512+128+j]+gbuf[768+128+j];
        float Go = gbuf[192+j]+gbuf[256+192+j]+gbuf[512+192+j]+gbuf[768+192+j];
        float cp = (t==0) ? 0.f : c1c[t-1][j];
        float cc = sigmf(Gf)*cp + sigmf(Gi)*tanhf(Gg);
        float hh = sigmf(Go)*tanhf(cc);
        c1c[t][j] = cc;
        srel(&h1buf[q*64+j], hh);
        srel(&h1cw[t*256 + q*64 + j], hh);
      }
      __syncthreads();
      if (tid == 0) fst(&flags[0+q], (unsigned)tauCnt);
      if (tid < 4 && tid != q){ while (fld(&flags[0+tid]) < (unsigned)tauCnt) __builtin_amdgcn_s_sleep(4); }
      __syncthreads();
      if (tid < HH) h1f[tid] = lrel(&h1buf[tid]);
      __syncthreads();
      // layer2: 512 virtual rows (Wih1 over h1f, Whh1 over h2f), k-split 2
      { int row2 = tid & 511, c2 = tid >> 9; int row = row2 & 255;
        const float4* W = (row2 < 256) ? We1ih : We1hh;
        const float* vin = (row2 < 256) ? h1f : h2f;
        float acc = 0.f;
#pragma unroll
        for (int i = 0; i < 32; ++i){
          float4 w = W[(c2*32+i)*256 + row];
          acc += dot4(w, *(const float4*)&vin[(c2*32+i)*4]);
        }
        if (c2 == 0 && row2 < 256) acc += b_e1[((row>>6)<<8) + (q<<6) + (row&63)];
        gbuf[c2*512 + row2] = acc;
      }
      __syncthreads();
      if (tid < 64){
        int j = tid;
        float Gi = gbuf[    j]+gbuf[256+    j]+gbuf[512+    j]+gbuf[768+    j];
        float Gf = gbuf[ 64+j]+gbuf[256+ 64+j]+gbuf[512+ 64+j]+gbuf[768+ 64+j];
        float Gg = gbuf[128+j]+gbuf[256+128+j]+gbuf[512+128+j]+gbuf[768+128+j];
        float Go = gbuf[192+j]+gbuf[256+192+j]+gbuf[512+192+j]+gbuf[768+192+j];
        float cp = (t==0) ? 0.f : c2c[t-1][j];
        float cc = sigmf(Gf)*cp + sigmf(Gi)*tanhf(Gg);
        float hh = sigmf(Go)*tanhf(cc);
        c2c[t][j] = cc;
        srel(&h2buf[q*64+j], hh);
        srel(&h2cw[t*256 + q*64 + j], hh);
      }
      __syncthreads();
      if (tid == 0) fst(&flags[4+q], (unsigned)tauCnt);
      if (tid < 4 && tid != q){ while (fld(&flags[4+tid]) < (unsigned)tauCnt) __builtin_amdgcn_s_sleep(4); }
      __syncthreads();
      if (tid < HH) h2f[tid] = lrel(&h2buf[tid]);
      __syncthreads();
      // eW1 row t (own 64 cols), 16-way k-split
      { int jl = tid & 63, ck = tid >> 6;
        float acc = 0.f;
#pragma unroll
        for (int i = 0; i < 4; ++i){
          float4 w = W1p[(ck*4+i)*64 + jl];
          acc += dot4(w, *(const float4*)&h2f[(ck*4+i)*4]);
        }
        gbuf[ck*64 + jl] = acc;
      }
      __syncthreads();
      if (tid < 64){
        float a = 0.f;
#pragma unroll
        for (int c = 0; c < 16; ++c) a += gbuf[c*64 + tid];
        eW1s[t][tid] = a;
      }
      __syncthreads();
      ++tauCnt;
    }
  };

  encode_from(0);

  // ---- decoder init: h,c = encoder finals; dec_in = enc0[:,0]
  if (tid < HH){ dh1f[tid] = h1f[tid]; dh2f[tid] = h2f[tid]; dins[tid] = lrel(&h2cw[tid]); }
  if (tid < 64){ dc1s[tid] = c1c[SS-1][tid]; dc2s[tid] = c2c[SS-1][tid]; }
  __syncthreads();

  int t0next = 0;
  for (int s = 0; s < SS; ++s){
    if (s > 0) encode_from(t0next);

    // ---- dec layer1 (Wd0ih over dins, Wd0hh over dh1f)
    { int row2 = tid & 511, c2 = tid >> 9; int row = row2 & 255;
      const float4* W = (row2 < 256) ? Wd0ih : Wd0hh;
      const float* vin = (row2 < 256) ? dins : dh1f;
      float acc = 0.f;
#pragma unroll
      for (int i = 0; i < 32; ++i){
        float4 w = W[(c2*32+i)*256 + row];
        acc += dot4(w, *(const float4*)&vin[(c2*32+i)*4]);
      }
      if (c2 == 0 && row2 < 256) acc += b_d0[((row>>6)<<8) + (q<<6) + (row&63)];
      gbuf[c2*512 + row2] = acc;
    }
    __syncthreads();
    if (tid < 64){
      int j = tid;
      float Gi = gbuf[    j]+gbuf[256+    j]+gbuf[512+    j]+gbuf[768+    j];
      float Gf = gbuf[ 64+j]+gbuf[256+ 64+j]+gbuf[512+ 64+j]+gbuf[768+ 64+j];
      float Gg = gbuf[128+j]+gbuf[256+128+j]+gbuf[512+128+j]+gbuf[768+128+j];
      float Go = gbuf[192+j]+gbuf[256+192+j]+gbuf[512+192+j]+gbuf[768+192+j];
      float cc = sigmf(Gf)*dc1s[j] + sigmf(Gi)*tanhf(Gg);
      float hh = sigmf(Go)*tanhf(cc);
      dc1s[j] = cc;
      srel(&dh1buf[q*64+j], hh);
    }
    __syncthreads();
    if (tid == 0) fst(&flags[8+q], (unsigned)(s+1));
    if (tid < 4 && tid != q){ while (fld(&flags[8+tid]) < (unsigned)(s+1)) __builtin_amdgcn_s_sleep(4); }
    __syncthreads();
    if (tid < HH) dh1f[tid] = lrel(&dh1buf[tid]);
    __syncthreads();
    // ---- dec layer2 (Wd1ih over dh1f, Wd1hh over dh2f)
    { int row2 = tid & 511, c2 = tid >> 9; int row = row2 & 255;
      const float4* W = (row2 < 256) ? Wd1ih : Wd1hh;
      const float* vin = (row2 < 256) ? dh1f : dh2f;
      float acc = 0.f;
#pragma unroll
      for (int i = 0; i < 32; ++i){
        float4 w = W[(c2*32+i)*256 + row];
        acc += dot4(w, *(const float4*)&vin[(c2*32+i)*4]);
      }
      if (c2 == 0 && row2 < 256) acc += b_d1[((row>>6)<<8) + (q<<6) + (row&63)];
      gbuf[c2*512 + row2] = acc;
    }
    __syncthreads();
    if (tid < 64){
      int j = tid;
      float Gi = gbuf[    j]+gbuf[256+    j]+gbuf[512+    j]+gbuf[768+    j];
      float Gf = gbuf[ 64+j]+gbuf[256+ 64+j]+gbuf[512+ 64+j]+gbuf[768+ 64+j];
      float Gg = gbuf[128+j]+gbuf[256+128+j]+gbuf[512+128+j]+gbuf[768+128+j];
      float Go = gbuf[192+j]+gbuf[256+192+j]+gbuf[512+192+j]+gbuf[768+192+j];
      float cc = sigmf(Gf)*dc2s[j] + sigmf(Gi)*tanhf(Gg);
      float hh = sigmf(Go)*tanhf(cc);
      dc2s[j] = cc;
      srel(&dh2buf[q*64+j], hh);
    }
    __syncthreads();
    if (tid == 0) fst(&flags[12+q], (unsigned)(s+1));
    if (tid < 4 && tid != q){ while (fld(&flags[12+tid]) < (unsigned)(s+1)) __builtin_amdgcn_s_sleep(4); }
    __syncthreads();
    if (tid < HH) dh2f[tid] = lrel(&dh2buf[tid]);
    __syncthreads();
    // ---- a2 = dec_out @ W2^T (own cols)
    { int jl = tid & 63, ck = tid >> 6;
      float acc = 0.f;
#pragma unroll
      for (int i = 0; i < 4; ++i){
        float4 w = W2p[(ck*4+i)*64 + jl];
        acc += dot4(w, *(const float4*)&dh2f[(ck*4+i)*4]);
      }
      gbuf[ck*64 + jl] = acc;
    }
    __syncthreads();
    if (tid < 64){
      float a = 0.f;
#pragma unroll
      for (int c = 0; c < 16; ++c) a += gbuf[c*64 + tid];
      a2s[tid] = a;
    }
    __syncthreads();
    // ---- partial scores over own cols: 16 lanes per t
    { int t = tid >> 4, r = tid & 15;
      float a = 0.f;
#pragma unroll
      for (int u = 0; u < 4; ++u){
        int jl = r + u*16;
        a += vv[q*64 + jl] * tanhf(eW1s[t][jl] + a2s[jl]);
      }
      a += __shfl_xor(a, 8, 16);
      a += __shfl_xor(a, 4, 16);
      a += __shfl_xor(a, 2, 16);
      a += __shfl_xor(a, 1, 16);
      if (r == 0) srel(&partbuf[q*64 + t], a);
    }
    __syncthreads();
    if (tid == 0) fst(&flags[16+q], (unsigned)(s+1));

    // ---- block0: gather partials, mask, softmax, argmax, publish idx
    if (q == 0){
      if (tid < 4 && tid != 0){ while (fld(&flags[16+tid]) < (unsigned)(s+1)) __builtin_amdgcn_s_sleep(4); }
      __syncthreads();
      if (tid < SS){
        float sv = lrel(&partbuf[tid]) + lrel(&partbuf[64+tid])
                 + lrel(&partbuf[128+tid]) + lrel(&partbuf[192+tid]);
        if (msk[tid]) sv = -3.0e38f;
        float m = sv; int mi = tid;
#pragma unroll
        for (int o = 32; o >= 1; o >>= 1){
          float ov = __shfl_xor(m, o, 64);
          int oi = __shfl_xor(mi, o, 64);
          if (ov > m || (ov == m && oi < mi)){ m = ov; mi = oi; }
        }
        float e = expf(sv - m);
        float ssum = e;
#pragma unroll
        for (int o = 32; o >= 1; o >>= 1) ssum += __shfl_xor(ssum, o, 64);
        out[((size_t)b*SS + s)*SS + tid] = e / ssum;
        if (tid == 0){
          msk[mi] = 1;
          out[(size_t)BB*SS*SS + (size_t)b*SS + s] = (float)mi;
          __hip_atomic_store(&flags[21], (unsigned)mi, __ATOMIC_RELAXED, __HIP_MEMORY_SCOPE_AGENT);
          fst(&flags[20], (unsigned)(s+1));
        }
      }
    }
    // ---- all blocks: wait idx
    if (tid == 0){
      while (fld(&flags[20]) < (unsigned)(s+1)) __builtin_amdgcn_s_sleep(4);
      seli = (int)__hip_atomic_load(&flags[21], __ATOMIC_RELAXED, __HIP_MEMORY_SCOPE_AGENT);
    }
    __syncthreads();
    int idx = seli;

    if (s < SS-1){
      // dec_in = enc_out[idx]; X1 row idx gains the last-feature flag
      if (tid < HH){
        dins[tid] = lrel(&h2cw[idx*256 + tid]);
        embt[tid] = tanhf(preE[idx][tid] + W_emb[tid*8 + 7]);
      }
      __syncthreads();
      { int row = tid & 255, c = tid >> 8;
        float acc = 0.f;
#pragma unroll
        for (int i = 0; i < 16; ++i){
          float4 w = We0ih[(c*16+i)*256 + row];
          acc += dot4(w, *(const float4*)&embt[(c*16+i)*4]);
        }
        gbuf[c*256 + row] = acc;
      }
      __syncthreads();
      if (tid < HH)
        X1[idx*256 + tid] = b_e0[((tid>>6)<<8) + (q<<6) + (tid&63)]
                          + gbuf[tid] + gbuf[256+tid] + gbuf[512+tid] + gbuf[768+tid];
      __syncthreads();
      // update handshake: nobody may start re-encoding (overwriting h2cw[idx])
      // until all 4 blocks consumed dins/h2cw for this step
      if (tid == 0) fst(&flags[24+q], (unsigned)(s+1));
      if (tid < 4 && tid != q){ while (fld(&flags[24+tid]) < (unsigned)(s+1)) __builtin_amdgcn_s_sleep(4); }
      __syncthreads();
      t0next = idx;
    }
  }
}

extern "C" void kernel_launch(void* const* d_in, const int* in_sizes, int n_in,
                              void* d_out, int out_size, void* d_ws, size_t ws_size,
                              hipStream_t stream) {
  const float* inputs = (const float*)d_in[0];
  const float* W_emb  = (const float*)d_in[1];
  const float* b_emb  = (const float*)d_in[2];
  const float* e_Wih0 = (const float*)d_in[3];
  const float* e_Whh0 = (const float*)d_in[4];
  const float* e_b0   = (const float*)d_in[5];
  const float* e_Wih1 = (const float*)d_in[6];
  const float* e_Whh1 = (const float*)d_in[7];
  const float* e_b1   = (const float*)d_in[8];
  const float* d_Wih0 = (const float*)d_in[9];
  const float* d_Whh0 = (const float*)d_in[10];
  const float* d_b0   = (const float*)d_in[11];
  const float* d_Wih1 = (const float*)d_in[12];
  const float* d_Whh1 = (const float*)d_in[13];
  const float* d_b1   = (const float*)d_in[14];
  const float* W1     = (const float*)d_in[15];
  const float* W2     = (const float*)d_in[16];
  const float* v      = (const float*)d_in[17];
  float* ws  = (float*)d_ws;
  float* out = (float*)d_out;

  zflags_k<<<dim3(1), dim3(1024), 0, stream>>>(ws);
  pack_k<<<dim3(2176), dim3(256), 0, stream>>>(
      e_Wih0, e_Whh0, e_Wih1, e_Whh1, d_Wih0, d_Whh0, d_Wih1, d_Whh1, W1, W2, ws);
  ptrnet_k<<<dim3(BB*4), dim3(NT), 0, stream>>>(
      inputs, W_emb, b_emb, e_b0, e_b1, d_b0, d_b1, v, ws, out);
}

// Round 4
// 56468.860 us; speedup vs baseline: 1.1649x; 1.1649x over previous
//
#include <hip/hip_runtime.h>
#include <math.h>

#define BB 32
#define SS 64
#define HH 256
#define NT 1024

// ws float offsets
//  [0]        weight packs: 8 gate mats x 4 slices x 16384 f4 + W1/W2 packs (2x4x4096 f4)
//  SH_OFF     per-batch shared: h1cw[64][256], h2cw[64][256], h1buf[256], h2buf[256],
//             dh1buf[256], dh2buf[256], partbuf[256]   (SHB floats each)
//  X1_OFF     per-block private X1 [64][256]
//  FLAGS_OFF  32 batches x 32 u32 flags
#define SH_OFF    2228224
#define SHB       34048
#define X1_OFF    3317760
#define FLAGS_OFF 5414912

__device__ __forceinline__ float sigmf(float x){ return 1.f/(1.f+expf(-x)); }
__device__ __forceinline__ float dot4(float4 a, float4 b){
  return fmaf(a.x,b.x,fmaf(a.y,b.y,fmaf(a.z,b.z,a.w*b.w)));
}
// RELAXED-ONLY atomics. Acquire/release at agent scope emit buffer_inv/buffer_wbl2
// (whole-L2 invalidate per spin poll!) on gfx950 — that was Round 3's 42GB FETCH storm.
// Ordering is done manually: payload stores -> s_waitcnt vmcnt(0) -> barrier -> flag store.
__device__ __forceinline__ void fst(unsigned* p, unsigned v){
  __hip_atomic_store(p, v, __ATOMIC_RELAXED, __HIP_MEMORY_SCOPE_AGENT);
}
__device__ __forceinline__ unsigned fld(unsigned* p){
  return __hip_atomic_load(p, __ATOMIC_RELAXED, __HIP_MEMORY_SCOPE_AGENT);
}
__device__ __forceinline__ void srel(float* p, float v){
  __hip_atomic_store(p, v, __ATOMIC_RELAXED, __HIP_MEMORY_SCOPE_AGENT);
}
__device__ __forceinline__ float lrel(const float* p){
  return __hip_atomic_load((float*)p, __ATOMIC_RELAXED, __HIP_MEMORY_SCOPE_AGENT);
}
__device__ __forceinline__ void drain_vm(){
  asm volatile("s_waitcnt vmcnt(0)" ::: "memory");
}

// Zero the flag words (stale seqnos from a previous call would deadlock/corrupt).
__global__ void zflags_k(float* ws){
  unsigned* f = (unsigned*)(ws + FLAGS_OFF);
  f[threadIdx.x] = 0u;   // 1024 = 32 batches x 32 words
}

// Pack weights into per-slice k-major float4 layout.
// Gate mats: dst4[(m*4+q)*16384 + kq*256 + r] = src_m[rowg][4kq..4kq+3],
//   rowg = (r>>6)*256 + q*64 + (r&63)  (r = gate*64 + jlocal)
// W1/W2: dst4[524288 + m2*16384 + q*4096 + kq*64 + jl] = src[(q*64+jl)][4kq..]
__global__ void pack_k(const float* __restrict__ e0ih, const float* __restrict__ e0hh,
                       const float* __restrict__ e1ih, const float* __restrict__ e1hh,
                       const float* __restrict__ d0ih, const float* __restrict__ d0hh,
                       const float* __restrict__ d1ih, const float* __restrict__ d1hh,
                       const float* __restrict__ W1,  const float* __restrict__ W2,
                       float* __restrict__ ws){
  const float* mats[8] = {e0ih,e0hh,e1ih,e1hh,d0ih,d0hh,d1ih,d1hh};
  float4* dst = (float4*)ws;
  int gid = blockIdx.x*256 + threadIdx.x;
  if (gid < 524288){
    int pack = gid >> 14, rem = gid & 16383;
    int m = pack >> 2, q = pack & 3;
    int kq = rem >> 8, r = rem & 255;
    int rowg = ((r>>6)<<8) + (q<<6) + (r&63);
    dst[gid] = *(const float4*)&mats[m][(size_t)rowg*256 + kq*4];
  } else {
    int g2 = gid - 524288;
    int m2 = g2 >> 14, rem = g2 & 16383;
    int q = rem >> 12, r2 = rem & 4095;
    int kq = r2 >> 6, jl = r2 & 63;
    const float* src = m2 ? W2 : W1;
    dst[524288 + m2*16384 + q*4096 + kq*64 + jl] =
      *(const float4*)&src[(size_t)(q*64+jl)*256 + kq*4];
  }
}

__global__ void __launch_bounds__(NT) ptrnet_k(
    const float* __restrict__ inputs, const float* __restrict__ W_emb,
    const float* __restrict__ b_emb,
    const float* __restrict__ b_e0, const float* __restrict__ b_e1,
    const float* __restrict__ b_d0, const float* __restrict__ b_d1,
    const float* __restrict__ vv,
    float* __restrict__ ws, float* __restrict__ out) {
  // XCD-colocation remap: XCD = blockIdx%8 (round-robin heuristic).
  // Put all blocks of slice q on XCDs {q, q+4} so each XCD's L2 holds exactly
  // one 2MB weight-slice set, shared by its 16 resident blocks.
  const int g = blockIdx.x;
  const int x = g & 7;
  const int q = x & 3;                       // slice (owns h-cols [64q,64q+64))
  const int b = ((g >> 3) << 1) | (x >> 2);  // batch
  const int tid = threadIdx.x;

  const float4* ws4 = (const float4*)ws;
  const float4* We0ih = ws4 + (0*4+q)*16384;
  const float4* We0hh = ws4 + (1*4+q)*16384;
  const float4* We1ih = ws4 + (2*4+q)*16384;
  const float4* We1hh = ws4 + (3*4+q)*16384;
  const float4* Wd0ih = ws4 + (4*4+q)*16384;
  const float4* Wd0hh = ws4 + (5*4+q)*16384;
  const float4* Wd1ih = ws4 + (6*4+q)*16384;
  const float4* Wd1hh = ws4 + (7*4+q)*16384;
  const float4* W1p = ws4 + 524288 + q*4096;
  const float4* W2p = ws4 + 524288 + 16384 + q*4096;

  float* shb   = ws + SH_OFF + (size_t)b*SHB;
  float* h1cw  = shb;            // [64][256] shared h1 cache
  float* h2cw  = shb + 16384;    // [64][256] shared h2 cache (= enc_out)
  float* h1buf = shb + 32768;    // [4][64] exchange
  float* h2buf = h1buf + 256;
  float* dh1buf= h2buf + 256;
  float* dh2buf= dh1buf + 256;
  float* partbuf=dh2buf + 256;   // [4][64] score partials
  unsigned* flags = ((unsigned*)(ws + FLAGS_OFF)) + b*32;
  // words: [0..3] enc-h1, [4..7] enc-h2, [8..11] dec-h1, [12..15] dec-h2,
  //        [16..19] partials, [20] packed ((s+1)<<8)|idx, [24..27] update handshake
  float* X1 = ws + X1_OFF + (size_t)g * 16384;  // [64][256 own gate rows]

  __shared__ float preE[SS][HH];   // pre-tanh embeddings (full)
  __shared__ float c1c[SS][64];    // own c slices per t
  __shared__ float c2c[SS][64];
  __shared__ float eW1s[SS][64];   // enc_out @ W1^T, own cols
  __shared__ float gbuf[1024];     // gate partial-reduce / staging (unioned)
  __shared__ float h1f[HH], h2f[HH], dh1f[HH], dh2f[HH], dins[HH], embt[HH];
  __shared__ float dc1s[64], dc2s[64], a2s[64];
  __shared__ int msk[SS];
  __shared__ int seli;

  // ---- phase 0: embed (pre-tanh) + init
  for (int i = tid; i < SS*HH; i += NT){
    int t = i >> 8, j = i & 255;
    const float* xr = inputs + ((size_t)b*SS + t)*8;
    float acc = b_emb[j];
#pragma unroll
    for (int d = 0; d < 8; ++d) acc = fmaf(xr[d], W_emb[j*8+d], acc);
    preE[t][j] = acc;
  }
  if (tid < HH){ h1f[tid] = 0.f; h2f[tid] = 0.f; }
  if (tid < SS) msk[tid] = 0;
  __syncthreads();

  // ---- phase 1: X1[t][own 256 gate rows] = b_e0 + tanh(preE[t]) @ Wih_e0^T
  for (int tile = 0; tile < 16; ++tile){
    { int tt = tid >> 8, j = tid & 255; gbuf[tid] = tanhf(preE[tile*4+tt][j]); }
    __syncthreads();
    { int row = tid >> 2, c = tid & 3;
      float a0=0.f,a1=0.f,a2v=0.f,a3=0.f;
#pragma unroll
      for (int i = 0; i < 16; ++i){
        float4 w = We0ih[(c*16+i)*256 + row];
        a0  += dot4(w, *(const float4*)&gbuf[  0 + (c*16+i)*4]);
        a1  += dot4(w, *(const float4*)&gbuf[256 + (c*16+i)*4]);
        a2v += dot4(w, *(const float4*)&gbuf[512 + (c*16+i)*4]);
        a3  += dot4(w, *(const float4*)&gbuf[768 + (c*16+i)*4]);
      }
      a0 += __shfl_xor(a0,1);  a0 += __shfl_xor(a0,2);
      a1 += __shfl_xor(a1,1);  a1 += __shfl_xor(a1,2);
      a2v+= __shfl_xor(a2v,1); a2v+= __shfl_xor(a2v,2);
      a3 += __shfl_xor(a3,1);  a3 += __shfl_xor(a3,2);
      if (c == 0){
        float bg = b_e0[((row>>6)<<8) + (q<<6) + (row&63)];
        X1[(tile*4+0)*256 + row] = bg + a0;
        X1[(tile*4+1)*256 + row] = bg + a1;
        X1[(tile*4+2)*256 + row] = bg + a2v;
        X1[(tile*4+3)*256 + row] = bg + a3;
      }
    }
    __syncthreads();
  }

  int tauCnt = 1;

  // ---- encoder from t0 (incremental restart; caches persist in LDS/ws)
  auto encode_from = [&](int t0){
    if (tid < HH){
      float v1 = 0.f, v2 = 0.f;
      if (t0 > 0){ v1 = lrel(&h1cw[(t0-1)*256 + tid]); v2 = lrel(&h2cw[(t0-1)*256 + tid]); }
      h1f[tid] = v1; h2f[tid] = v2;
    }
    __syncthreads();
    for (int t = t0; t < SS; ++t){
      // layer1: own 256 gate rows, k-split 4
      { int row = tid & 255, c = tid >> 8;
        float acc = 0.f;
#pragma unroll
        for (int i = 0; i < 16; ++i){
          float4 w = We0hh[(c*16+i)*256 + row];
          acc += dot4(w, *(const float4*)&h1f[(c*16+i)*4]);
        }
        gbuf[c*256+row] = (c==0) ? acc + X1[t*256+row] : acc;
      }
      __syncthreads();
      if (tid < 64){
        int j = tid;
        float Gi = gbuf[    j]+gbuf[256+    j]+gbuf[512+    j]+gbuf[768+    j];
        float Gf = gbuf[ 64+j]+gbuf[256+ 64+j]+gbuf[512+ 64+j]+gbuf[768+ 64+j];
        float Gg = gbuf[128+j]+gbuf[256+128+j]+gbuf[512+128+j]+gbuf[768+128+j];
        float Go = gbuf[192+j]+gbuf[256+192+j]+gbuf[512+192+j]+gbuf[768+192+j];
        float cp = (t==0) ? 0.f : c1c[t-1][j];
        float cc = sigmf(Gf)*cp + sigmf(Gi)*tanhf(Gg);
        float hh = sigmf(Go)*tanhf(cc);
        c1c[t][j] = cc;
        srel(&h1buf[q*64+j], hh);
        srel(&h1cw[t*256 + q*64 + j], hh);
      }
      drain_vm();
      __syncthreads();
      if (tid == 0) fst(&flags[0+q], (unsigned)tauCnt);
      if (tid < 4 && tid != q){ while (fld(&flags[0+tid]) < (unsigned)tauCnt) __builtin_amdgcn_s_sleep(2); }
      __syncthreads();
      if (tid < HH) h1f[tid] = lrel(&h1buf[tid]);
      __syncthreads();
      // layer2: 512 virtual rows (Wih1 over h1f, Whh1 over h2f), k-split 2
      { int row2 = tid & 511, c2 = tid >> 9; int row = row2 & 255;
        const float4* W = (row2 < 256) ? We1ih : We1hh;
        const float* vin = (row2 < 256) ? h1f : h2f;
        float acc = 0.f;
#pragma unroll
        for (int i = 0; i < 32; ++i){
          float4 w = W[(c2*32+i)*256 + row];
          acc += dot4(w, *(const float4*)&vin[(c2*32+i)*4]);
        }
        if (c2 == 0 && row2 < 256) acc += b_e1[((row>>6)<<8) + (q<<6) + (row&63)];
        gbuf[c2*512 + row2] = acc;
      }
      __syncthreads();
      if (tid < 64){
        int j = tid;
        float Gi = gbuf[    j]+gbuf[256+    j]+gbuf[512+    j]+gbuf[768+    j];
        float Gf = gbuf[ 64+j]+gbuf[256+ 64+j]+gbuf[512+ 64+j]+gbuf[768+ 64+j];
        float Gg = gbuf[128+j]+gbuf[256+128+j]+gbuf[512+128+j]+gbuf[768+128+j];
        float Go = gbuf[192+j]+gbuf[256+192+j]+gbuf[512+192+j]+gbuf[768+192+j];
        float cp = (t==0) ? 0.f : c2c[t-1][j];
        float cc = sigmf(Gf)*cp + sigmf(Gi)*tanhf(Gg);
        float hh = sigmf(Go)*tanhf(cc);
        c2c[t][j] = cc;
        srel(&h2buf[q*64+j], hh);
        srel(&h2cw[t*256 + q*64 + j], hh);
      }
      drain_vm();
      __syncthreads();
      if (tid == 0) fst(&flags[4+q], (unsigned)tauCnt);
      if (tid < 4 && tid != q){ while (fld(&flags[4+tid]) < (unsigned)tauCnt) __builtin_amdgcn_s_sleep(2); }
      __syncthreads();
      if (tid < HH) h2f[tid] = lrel(&h2buf[tid]);
      __syncthreads();
      // eW1 row t (own 64 cols), 16-way k-split
      { int jl = tid & 63, ck = tid >> 6;
        float acc = 0.f;
#pragma unroll
        for (int i = 0; i < 4; ++i){
          float4 w = W1p[(ck*4+i)*64 + jl];
          acc += dot4(w, *(const float4*)&h2f[(ck*4+i)*4]);
        }
        gbuf[ck*64 + jl] = acc;
      }
      __syncthreads();
      if (tid < 64){
        float a = 0.f;
#pragma unroll
        for (int c = 0; c < 16; ++c) a += gbuf[c*64 + tid];
        eW1s[t][tid] = a;
      }
      __syncthreads();
      ++tauCnt;
    }
  };

  encode_from(0);

  // ---- decoder init: h,c = encoder finals; dec_in = enc0[:,0]
  if (tid < HH){ dh1f[tid] = h1f[tid]; dh2f[tid] = h2f[tid]; dins[tid] = lrel(&h2cw[tid]); }
  if (tid < 64){ dc1s[tid] = c1c[SS-1][tid]; dc2s[tid] = c2c[SS-1][tid]; }
  __syncthreads();

  int t0next = 0;
  for (int s = 0; s < SS; ++s){
    if (s > 0) encode_from(t0next);

    // ---- dec layer1 (Wd0ih over dins, Wd0hh over dh1f)
    { int row2 = tid & 511, c2 = tid >> 9; int row = row2 & 255;
      const float4* W = (row2 < 256) ? Wd0ih : Wd0hh;
      const float* vin = (row2 < 256) ? dins : dh1f;
      float acc = 0.f;
#pragma unroll
      for (int i = 0; i < 32; ++i){
        float4 w = W[(c2*32+i)*256 + row];
        acc += dot4(w, *(const float4*)&vin[(c2*32+i)*4]);
      }
      if (c2 == 0 && row2 < 256) acc += b_d0[((row>>6)<<8) + (q<<6) + (row&63)];
      gbuf[c2*512 + row2] = acc;
    }
    __syncthreads();
    if (tid < 64){
      int j = tid;
      float Gi = gbuf[    j]+gbuf[256+    j]+gbuf[512+    j]+gbuf[768+    j];
      float Gf = gbuf[ 64+j]+gbuf[256+ 64+j]+gbuf[512+ 64+j]+gbuf[768+ 64+j];
      float Gg = gbuf[128+j]+gbuf[256+128+j]+gbuf[512+128+j]+gbuf[768+128+j];
      float Go = gbuf[192+j]+gbuf[256+192+j]+gbuf[512+192+j]+gbuf[768+192+j];
      float cc = sigmf(Gf)*dc1s[j] + sigmf(Gi)*tanhf(Gg);
      float hh = sigmf(Go)*tanhf(cc);
      dc1s[j] = cc;
      srel(&dh1buf[q*64+j], hh);
    }
    drain_vm();
    __syncthreads();
    if (tid == 0) fst(&flags[8+q], (unsigned)(s+1));
    if (tid < 4 && tid != q){ while (fld(&flags[8+tid]) < (unsigned)(s+1)) __builtin_amdgcn_s_sleep(2); }
    __syncthreads();
    if (tid < HH) dh1f[tid] = lrel(&dh1buf[tid]);
    __syncthreads();
    // ---- dec layer2 (Wd1ih over dh1f, Wd1hh over dh2f)
    { int row2 = tid & 511, c2 = tid >> 9; int row = row2 & 255;
      const float4* W = (row2 < 256) ? Wd1ih : Wd1hh;
      const float* vin = (row2 < 256) ? dh1f : dh2f;
      float acc = 0.f;
#pragma unroll
      for (int i = 0; i < 32; ++i){
        float4 w = W[(c2*32+i)*256 + row];
        acc += dot4(w, *(const float4*)&vin[(c2*32+i)*4]);
      }
      if (c2 == 0 && row2 < 256) acc += b_d1[((row>>6)<<8) + (q<<6) + (row&63)];
      gbuf[c2*512 + row2] = acc;
    }
    __syncthreads();
    if (tid < 64){
      int j = tid;
      float Gi = gbuf[    j]+gbuf[256+    j]+gbuf[512+    j]+gbuf[768+    j];
      float Gf = gbuf[ 64+j]+gbuf[256+ 64+j]+gbuf[512+ 64+j]+gbuf[768+ 64+j];
      float Gg = gbuf[128+j]+gbuf[256+128+j]+gbuf[512+128+j]+gbuf[768+128+j];
      float Go = gbuf[192+j]+gbuf[256+192+j]+gbuf[512+192+j]+gbuf[768+192+j];
      float cc = sigmf(Gf)*dc2s[j] + sigmf(Gi)*tanhf(Gg);
      float hh = sigmf(Go)*tanhf(cc);
      dc2s[j] = cc;
      srel(&dh2buf[q*64+j], hh);
    }
    drain_vm();
    __syncthreads();
    if (tid == 0) fst(&flags[12+q], (unsigned)(s+1));
    if (tid < 4 && tid != q){ while (fld(&flags[12+tid]) < (unsigned)(s+1)) __builtin_amdgcn_s_sleep(2); }
    __syncthreads();
    if (tid < HH) dh2f[tid] = lrel(&dh2buf[tid]);
    __syncthreads();
    // ---- a2 = dec_out @ W2^T (own cols)
    { int jl = tid & 63, ck = tid >> 6;
      float acc = 0.f;
#pragma unroll
      for (int i = 0; i < 4; ++i){
        float4 w = W2p[(ck*4+i)*64 + jl];
        acc += dot4(w, *(const float4*)&dh2f[(ck*4+i)*4]);
      }
      gbuf[ck*64 + jl] = acc;
    }
    __syncthreads();
    if (tid < 64){
      float a = 0.f;
#pragma unroll
      for (int c = 0; c < 16; ++c) a += gbuf[c*64 + tid];
      a2s[tid] = a;
    }
    __syncthreads();
    // ---- partial scores over own cols: 16 lanes per t
    { int t = tid >> 4, r = tid & 15;
      float a = 0.f;
#pragma unroll
      for (int u = 0; u < 4; ++u){
        int jl = r + u*16;
        a += vv[q*64 + jl] * tanhf(eW1s[t][jl] + a2s[jl]);
      }
      a += __shfl_xor(a, 8, 16);
      a += __shfl_xor(a, 4, 16);
      a += __shfl_xor(a, 2, 16);
      a += __shfl_xor(a, 1, 16);
      if (r == 0) srel(&partbuf[q*64 + t], a);
    }
    drain_vm();
    __syncthreads();
    if (tid == 0) fst(&flags[16+q], (unsigned)(s+1));

    // ---- block q0: gather partials, mask, softmax, argmax, publish packed idx
    if (q == 0){
      if (tid < 4 && tid != 0){ while (fld(&flags[16+tid]) < (unsigned)(s+1)) __builtin_amdgcn_s_sleep(2); }
      __syncthreads();
      if (tid < SS){
        float sv = lrel(&partbuf[tid]) + lrel(&partbuf[64+tid])
                 + lrel(&partbuf[128+tid]) + lrel(&partbuf[192+tid]);
        if (msk[tid]) sv = -3.0e38f;
        float m = sv; int mi = tid;
#pragma unroll
        for (int o = 32; o >= 1; o >>= 1){
          float ov = __shfl_xor(m, o, 64);
          int oi = __shfl_xor(mi, o, 64);
          if (ov > m || (ov == m && oi < mi)){ m = ov; mi = oi; }
        }
        float e = expf(sv - m);
        float ssum = e;
#pragma unroll
        for (int o = 32; o >= 1; o >>= 1) ssum += __shfl_xor(ssum, o, 64);
        out[((size_t)b*SS + s)*SS + tid] = e / ssum;
        if (tid == 0){
          msk[mi] = 1;
          out[(size_t)BB*SS*SS + (size_t)b*SS + s] = (float)mi;
          // packed seq|idx: single word, no store-store ordering needed
          fst(&flags[20], ((unsigned)(s+1) << 8) | (unsigned)mi);
        }
      }
    }
    // ---- all blocks: wait packed idx
    if (tid == 0){
      unsigned w;
      while (((w = fld(&flags[20])) >> 8) < (unsigned)(s+1)) __builtin_amdgcn_s_sleep(2);
      seli = (int)(w & 255u);
    }
    __syncthreads();
    int idx = seli;

    if (s < SS-1){
      // dec_in = enc_out[idx]; X1 row idx gains the last-feature flag
      if (tid < HH){
        dins[tid] = lrel(&h2cw[idx*256 + tid]);
        embt[tid] = tanhf(preE[idx][tid] + W_emb[tid*8 + 7]);
      }
      __syncthreads();
      { int row = tid & 255, c = tid >> 8;
        float acc = 0.f;
#pragma unroll
        for (int i = 0; i < 16; ++i){
          float4 w = We0ih[(c*16+i)*256 + row];
          acc += dot4(w, *(const float4*)&embt[(c*16+i)*4]);
        }
        gbuf[c*256 + row] = acc;
      }
      __syncthreads();
      if (tid < HH)
        X1[idx*256 + tid] = b_e0[((tid>>6)<<8) + (q<<6) + (tid&63)]
                          + gbuf[tid] + gbuf[256+tid] + gbuf[512+tid] + gbuf[768+tid];
      drain_vm();
      __syncthreads();
      // update handshake: nobody may re-encode (overwriting h2cw[idx]) until all
      // 4 blocks consumed dins/h2cw for this step
      if (tid == 0) fst(&flags[24+q], (unsigned)(s+1));
      if (tid < 4 && tid != q){ while (fld(&flags[24+tid]) < (unsigned)(s+1)) __builtin_amdgcn_s_sleep(2); }
      __syncthreads();
      t0next = idx;
    }
  }
}

extern "C" void kernel_launch(void* const* d_in, const int* in_sizes, int n_in,
                              void* d_out, int out_size, void* d_ws, size_t ws_size,
                              hipStream_t stream) {
  const float* inputs = (const float*)d_in[0];
  const float* W_emb  = (const float*)d_in[1];
  const float* b_emb  = (const float*)d_in[2];
  const float* e_Wih0 = (const float*)d_in[3];
  const float* e_Whh0 = (const float*)d_in[4];
  const float* e_b0   = (const float*)d_in[5];
  const float* e_Wih1 = (const float*)d_in[6];
  const float* e_Whh1 = (const float*)d_in[7];
  const float* e_b1   = (const float*)d_in[8];
  const float* d_Wih0 = (const float*)d_in[9];
  const float* d_Whh0 = (const float*)d_in[10];
  const float* d_b0   = (const float*)d_in[11];
  const float* d_Wih1 = (const float*)d_in[12];
  const float* d_Whh1 = (const float*)d_in[13];
  const float* d_b1   = (const float*)d_in[14];
  const float* W1     = (const float*)d_in[15];
  const float* W2     = (const float*)d_in[16];
  const float* v      = (const float*)d_in[17];
  float* ws  = (float*)d_ws;
  float* out = (float*)d_out;

  zflags_k<<<dim3(1), dim3(1024), 0, stream>>>(ws);
  pack_k<<<dim3(2176), dim3(256), 0, stream>>>(
      e_Wih0, e_Whh0, e_Wih1, e_Whh1, d_Wih0, d_Whh0, d_Wih1, d_Whh1, W1, W2, ws);
  ptrnet_k<<<dim3(BB*4), dim3(NT), 0, stream>>>(
      inputs, W_emb, b_emb, e_b0, e_b1, d_b0, d_b1, v, ws, out);
}

// Round 7
// 23085.884 us; speedup vs baseline: 2.8493x; 2.4460x over previous
//
#include <hip/hip_runtime.h>
#include <math.h>

#define BB 32
#define SS 64
#define HH 256
#define G4 1024
#define NT 1024

// ws float offsets
//  [0]        8 gate mats packed k-major f4 (R2 format), 262144 floats each
//  W1T_OFF    W1T k-major 256x256; W2T_OFF likewise
//  PB_OFF     per-batch: X1[64][1024], h1cw[64][256], p2 ring[16][1024],
//             h2cw[64][256], dc1i[256], dc2i[256], embt[256]
//  FLG_OFF    per-batch flags[8]: 0=progA 1=progB 2=progC 3=idxpack; +256 abort
#define W1T_OFF 2097152
#define W2T_OFF 2162688
#define PB_OFF  2228224
#define PBB     115712
#define OX1     0
#define OH1     65536
#define OP2     81920
#define OH2     98304
#define ODC1    114688
#define ODC2    114944
#define OEMB    115200
#define FLG_OFF (PB_OFF + 32*PBB)

__device__ __forceinline__ float sigmf(float x){ return 1.f/(1.f+expf(-x)); }
__device__ __forceinline__ float dot4(float4 a, float4 b){
  return fmaf(a.x,b.x,fmaf(a.y,b.y,fmaf(a.z,b.z,a.w*b.w)));
}
// Transport: relaxed agent-scope atomics (R4-proven LLC-coherent on any XCD;
// no acquire/release -> no L2-invalidate storms). Ordering: payload srel ->
// drain_vm -> __syncthreads -> flag fst.
__device__ __forceinline__ void fst(unsigned* p, unsigned v){
  __hip_atomic_store(p, v, __ATOMIC_RELAXED, __HIP_MEMORY_SCOPE_AGENT);
}
__device__ __forceinline__ unsigned fld(unsigned* p){
  return __hip_atomic_load(p, __ATOMIC_RELAXED, __HIP_MEMORY_SCOPE_AGENT);
}
__device__ __forceinline__ void srel(float* p, float v){
  __hip_atomic_store(p, v, __ATOMIC_RELAXED, __HIP_MEMORY_SCOPE_AGENT);
}
__device__ __forceinline__ float lrel(const float* p){
  return __hip_atomic_load((float*)p, __ATOMIC_RELAXED, __HIP_MEMORY_SCOPE_AGENT);
}
__device__ __forceinline__ void drain_vm(){
  asm volatile("s_waitcnt vmcnt(0)" ::: "memory");
}
// Capped one-directional wait; abort latch terminates (fails loudly) instead
// of hanging if the protocol is ever broken.
__device__ __forceinline__ int wait_ge(unsigned* p, unsigned want, unsigned* ab){
  int it = 0;
  for(;;){
    unsigned v = fld(p);
    if (v >= want) return (int)v;
    if ((++it & 2047) == 0){
      if (fld(ab) != 0u) return -1;
      if (it > (1<<23)){ fst(ab, 1u); return -1; }
    }
    __builtin_amdgcn_s_sleep(2);
  }
}

__global__ void zflags_k(float* ws){
  unsigned* f = (unsigned*)(ws + FLG_OFF);
  if (threadIdx.x < 512) f[threadIdx.x] = 0u;
}

// R2-validated pack: dst[((k>>2)*1024 + g)*4 + (k&3)] = src[g*256 + k]
__global__ void pack_transpose_k(const float* __restrict__ s0, const float* __restrict__ s1,
                                 const float* __restrict__ s2, const float* __restrict__ s3,
                                 const float* __restrict__ s4, const float* __restrict__ s5,
                                 const float* __restrict__ s6, const float* __restrict__ s7,
                                 float* __restrict__ ws) {
    __shared__ float tile[64][65];
    const float* srcs[8] = {s0, s1, s2, s3, s4, s5, s6, s7};
    const float* src = srcs[blockIdx.z];
    float* dst = ws + (size_t)blockIdx.z * (G4 * HH);
    int gblk = blockIdx.x * 64;
    int kblk = blockIdx.y * 64;
    for (int q = threadIdx.x; q < 64 * 64; q += 256) {
        int r = q >> 6, c = q & 63;
        tile[r][c] = src[(size_t)(gblk + r) * HH + (kblk + c)];
    }
    __syncthreads();
    for (int q = threadIdx.x; q < 64 * 64; q += 256) {
        int r = q & 3;
        int gl = (q >> 2) & 63;
        int k0l = q >> 8;
        int dsti = (((kblk >> 2) + k0l) * G4 + gblk + gl) * 4 + r;
        dst[dsti] = tile[gl][k0l * 4 + r];
    }
}

// R2-validated: dst[k*256+j] = src[j*256+k]
__global__ void transpose256_k(const float* __restrict__ W1, const float* __restrict__ W2,
                               float* __restrict__ ws) {
    __shared__ float tile[32][33];
    const float* src = blockIdx.z ? W2 : W1;
    float* dst = ws + (blockIdx.z ? W2T_OFF : W1T_OFF);
    int j0 = blockIdx.x * 32, k0 = blockIdx.y * 32;
    int tx = threadIdx.x & 31, ty = threadIdx.x >> 5;
    for (int i = ty; i < 32; i += 8) tile[i][tx] = src[(size_t)(j0 + i) * HH + k0 + tx];
    __syncthreads();
    for (int i = ty; i < 32; i += 8) dst[(size_t)(k0 + i) * HH + j0 + tx] = tile[tx][i];
}

__global__ void __launch_bounds__(NT) ptrnet_k(
    const float* __restrict__ inputs, const float* __restrict__ W_emb,
    const float* __restrict__ b_emb,
    const float* __restrict__ b_e0, const float* __restrict__ b_e1,
    const float* __restrict__ b_d0, const float* __restrict__ b_d1,
    const float* __restrict__ vv,
    float* __restrict__ ws, float* __restrict__ out) {
  const int g = blockIdx.x;
  const int role = g & 3;   // A/B/C/D; with %8 XCD striping each XCD hosts 1 role
  const int b = g >> 2;
  const int tid = threadIdx.x;

  const float4* ws4 = (const float4*)ws;
  const float4* We0ih = ws4 + 0*65536;
  const float4* We0hh = ws4 + 1*65536;
  const float4* We1ih = ws4 + 2*65536;
  const float4* We1hh = ws4 + 3*65536;
  const float4* Wd0ih = ws4 + 4*65536;
  const float4* Wd0hh = ws4 + 5*65536;
  const float4* Wd1ih = ws4 + 6*65536;
  const float4* Wd1hh = ws4 + 7*65536;
  const float* W1T = ws + W1T_OFF;
  const float* W2T = ws + W2T_OFF;

  float* pb   = ws + PB_OFF + (size_t)b * PBB;
  float* X1   = pb + OX1;    // A-private (plain ld/st)
  float* h1cw = pb + OH1;    // A -> B (+A restart)
  float* p2cw = pb + OP2;    // B -> C, ring of 16
  float* h2cw = pb + OH2;    // C -> D (+C restart)
  float* dc1i = pb + ODC1;   // A -> D (pass-0 finals)
  float* dc2i = pb + ODC2;   // C -> D
  float* embw = pb + OEMB;   // D -> A
  unsigned* flg = (unsigned*)(ws + FLG_OFF) + b*8;
  unsigned* abw = (unsigned*)(ws + FLG_OFF) + 256;

  __shared__ float big0[16384];  // A: preE->c1c; C: c2c; D: preE
  __shared__ float big1[16384];  // D: eW1
  __shared__ float gbuf[1024];
  __shared__ float v0[256], v1[256], v2[256], v3[256], v4[256], v5[256], v6[256];
  __shared__ float scr[64];
  __shared__ int msk[64];
  __shared__ int ibc[2];

  // ================= role A: layer-1 recurrence =================
  if (role == 0) {
    for (int i = tid; i < SS*HH; i += NT){
      int t = i >> 8, j = i & 255;
      const float* xr = inputs + ((size_t)b*SS + t)*8;
      float acc = b_emb[j];
#pragma unroll
      for (int d = 0; d < 8; ++d) acc = fmaf(xr[d], W_emb[j*8+d], acc);
      big0[i] = acc;  // preE
    }
    __syncthreads();
    // X1 init: 16 tiles of 4 t (weights read once per 4 rows)
    for (int tile = 0; tile < 16; ++tile){
      { int tt = tid >> 8, j = tid & 255; gbuf[tid] = tanhf(big0[(tile*4+tt)*256 + j]); }
      __syncthreads();
      float a0=0.f,a1=0.f,a2=0.f,a3=0.f;
      for (int kq = 0; kq < 64; ++kq){
        float4 w = We0ih[(kq<<10) + tid];
        a0 += dot4(w, *(const float4*)&gbuf[   0 + kq*4]);
        a1 += dot4(w, *(const float4*)&gbuf[ 256 + kq*4]);
        a2 += dot4(w, *(const float4*)&gbuf[ 512 + kq*4]);
        a3 += dot4(w, *(const float4*)&gbuf[ 768 + kq*4]);
      }
      float bg = b_e0[tid];
      X1[(tile*4+0)*1024 + tid] = bg + a0;
      X1[(tile*4+1)*1024 + tid] = bg + a1;
      X1[(tile*4+2)*1024 + tid] = bg + a2;
      X1[(tile*4+3)*1024 + tid] = bg + a3;
      __syncthreads();
    }
    // big0 becomes c1c from here
    if (tid < 256) v0[tid] = 0.f;  // h1
    __syncthreads();
    int tau = 0;
    for (int p = 0; p < SS; ++p){
      int t0 = 0;
      if (p > 0){
        if (tid == 0){
          int iv = wait_ge(&flg[3], (unsigned)p << 8, abw);
          ibc[0] = (iv < 0) ? 0 : (iv & 255);
        }
        __syncthreads();
        t0 = ibc[0];
        if (tid < 256) v1[tid] = lrel(&embw[tid]);
        __syncthreads();
        { float acc = 0.f;  // X1 row t0 update (A-private, plain store)
          for (int kq = 0; kq < 64; ++kq){
            float4 w = We0ih[(kq<<10) + tid];
            acc += dot4(w, *(const float4*)&v1[kq*4]);
          }
          X1[t0*1024 + tid] = b_e0[tid] + acc; }
        if (tid < 256) v0[tid] = (t0 > 0) ? lrel(&h1cw[(t0-1)*256 + tid]) : 0.f;
        __syncthreads();
      }
      for (int t = t0; t < SS; ++t){
        ++tau;
        { float acc = X1[t*1024 + tid];
          for (int kq = 0; kq < 64; ++kq){
            float4 w = We0hh[(kq<<10) + tid];
            acc += dot4(w, *(const float4*)&v0[kq*4]);
          }
          gbuf[tid] = acc; }
        __syncthreads();
        if (tid < 256){
          float Gi = gbuf[tid], Gf = gbuf[tid+256], Gg = gbuf[tid+512], Go = gbuf[tid+768];
          float cp = (t == 0) ? 0.f : big0[(t-1)*256 + tid];
          float cc = sigmf(Gf)*cp + sigmf(Gi)*tanhf(Gg);
          float hh = sigmf(Go)*tanhf(cc);
          big0[t*256 + tid] = cc; v0[tid] = hh;
          srel(&h1cw[t*256 + tid], hh);
          if (p == 0 && t == SS-1) srel(&dc1i[tid], cc);
        }
        drain_vm();
        __syncthreads();
        if (tid == 0) fst(&flg[0], (unsigned)tau);
      }
    }
  }
  // ================= role B: p2(t) = b_e1 + Wih1 . h1(t) =================
  else if (role == 1) {
    int tau = 0;
    for (int p = 0; p < SS; ++p){
      int t0 = 0;
      if (p > 0){
        if (tid == 0){
          int iv = wait_ge(&flg[3], (unsigned)p << 8, abw);
          ibc[0] = (iv < 0) ? 0 : (iv & 255);
        }
        __syncthreads();
        t0 = ibc[0];
      }
      for (int t = t0; t < SS; ++t){
        ++tau;
        if (tid == 0){
          wait_ge(&flg[0], (unsigned)tau, abw);                       // progA
          if (tau > 16) wait_ge(&flg[2], (unsigned)(tau-16), abw);    // ring backpressure
        }
        __syncthreads();
        if (tid < 256) v0[tid] = lrel(&h1cw[t*256 + tid]);
        __syncthreads();
        float acc = b_e1[tid];
        for (int kq = 0; kq < 64; ++kq){
          float4 w = We1ih[(kq<<10) + tid];
          acc += dot4(w, *(const float4*)&v0[kq*4]);
        }
        srel(&p2cw[(tau & 15)*1024 + tid], acc);
        drain_vm();
        __syncthreads();
        if (tid == 0) fst(&flg[1], (unsigned)tau);
      }
    }
  }
  // ================= role C: layer-2 recurrence =================
  else if (role == 2) {
    int tau = 0;
    for (int p = 0; p < SS; ++p){
      int t0 = 0;
      if (p > 0){
        if (tid == 0){
          int iv = wait_ge(&flg[3], (unsigned)p << 8, abw);
          ibc[0] = (iv < 0) ? 0 : (iv & 255);
        }
        __syncthreads();
        t0 = ibc[0];
      }
      if (tid < 256) v0[tid] = (t0 > 0) ? lrel(&h2cw[(t0-1)*256 + tid]) : 0.f;
      __syncthreads();
      for (int t = t0; t < SS; ++t){
        ++tau;
        if (tid == 0) wait_ge(&flg[1], (unsigned)tau, abw);
        __syncthreads();
        float acc = lrel(&p2cw[(tau & 15)*1024 + tid]);
        for (int kq = 0; kq < 64; ++kq){
          float4 w = We1hh[(kq<<10) + tid];
          acc += dot4(w, *(const float4*)&v0[kq*4]);
        }
        gbuf[tid] = acc;
        __syncthreads();
        if (tid < 256){
          float Gi = gbuf[tid], Gf = gbuf[tid+256], Gg = gbuf[tid+512], Go = gbuf[tid+768];
          float cp = (t == 0) ? 0.f : big0[(t-1)*256 + tid];   // c2c
          float cc = sigmf(Gf)*cp + sigmf(Gi)*tanhf(Gg);
          float hh = sigmf(Go)*tanhf(cc);
          big0[t*256 + tid] = cc; v0[tid] = hh;
          srel(&h2cw[t*256 + tid], hh);
          if (p == 0 && t == SS-1) srel(&dc2i[tid], cc);
        }
        drain_vm();
        __syncthreads();
        if (tid == 0) fst(&flg[2], (unsigned)tau);
      }
    }
  }
  // ================= role D: eW1, decoder cell, attention, argmax =================
  else {
    for (int i = tid; i < SS*HH; i += NT){
      int t = i >> 8, j = i & 255;
      const float* xr = inputs + ((size_t)b*SS + t)*8;
      float acc = b_emb[j];
#pragma unroll
      for (int d = 0; d < 8; ++d) acc = fmaf(xr[d], W_emb[j*8+d], acc);
      big0[i] = acc;  // preE, kept whole run
    }
    if (tid < 64) msk[tid] = 0;
    __syncthreads();

    // v2=dins v3=dh1 v4=dc1 v5=dh2 v6=dc2 v1=a2
    auto dec_cell = [&](){
      { float acc = b_d0[tid];
        for (int kq = 0; kq < 64; ++kq){
          acc += dot4(Wd0ih[(kq<<10) + tid], *(const float4*)&v2[kq*4]);
          acc += dot4(Wd0hh[(kq<<10) + tid], *(const float4*)&v3[kq*4]);
        }
        gbuf[tid] = acc; }
      __syncthreads();
      if (tid < 256){
        float Gi = gbuf[tid], Gf = gbuf[tid+256], Gg = gbuf[tid+512], Go = gbuf[tid+768];
        float cc = sigmf(Gf)*v4[tid] + sigmf(Gi)*tanhf(Gg);
        float hh = sigmf(Go)*tanhf(cc);
        v4[tid] = cc; v3[tid] = hh;
      }
      __syncthreads();
      { float acc = b_d1[tid];
        for (int kq = 0; kq < 64; ++kq){
          acc += dot4(Wd1ih[(kq<<10) + tid], *(const float4*)&v3[kq*4]);
          acc += dot4(Wd1hh[(kq<<10) + tid], *(const float4*)&v5[kq*4]);
        }
        gbuf[tid] = acc; }
      __syncthreads();
      if (tid < 256){
        float Gi = gbuf[tid], Gf = gbuf[tid+256], Gg = gbuf[tid+512], Go = gbuf[tid+768];
        float cc = sigmf(Gf)*v6[tid] + sigmf(Gi)*tanhf(Gg);
        float hh = sigmf(Go)*tanhf(cc);
        v6[tid] = cc; v5[tid] = hh;
      }
      __syncthreads();
      { int j = tid & 255, c = tid >> 8;   // a2 = dh2 @ W2^T
        float a = 0.f;
        for (int k = c*64; k < c*64 + 64; ++k) a = fmaf(v5[k], W2T[k*256 + j], a);
        gbuf[tid] = a; }
      __syncthreads();
      if (tid < 256) v1[tid] = gbuf[tid] + gbuf[tid+256] + gbuf[tid+512] + gbuf[tid+768];
      __syncthreads();
    };

    int tau = 0, lastidx = 0;
    for (int p = 0; p < SS; ++p){
      int t0 = (p == 0) ? 0 : lastidx;
      if (p > 0) dec_cell();   // overlaps with upstream encode pass
      for (int t = t0; t < SS; ++t){
        ++tau;
        if (tid == 0) wait_ge(&flg[2], (unsigned)tau, abw);
        __syncthreads();
        if (tid < 256) v0[tid] = lrel(&h2cw[t*256 + tid]);
        __syncthreads();
        { int j = tid & 255, c = tid >> 8;   // eW1 row t
          float a = 0.f;
          for (int k = c*64; k < c*64 + 64; ++k) a = fmaf(v0[k], W1T[k*256 + j], a);
          gbuf[tid] = a; }
        __syncthreads();
        if (tid < 256) big1[t*256 + tid] = gbuf[tid] + gbuf[tid+256] + gbuf[tid+512] + gbuf[tid+768];
        __syncthreads();
      }
      if (p == 0){
        if (tid < 256){
          v3[tid] = lrel(&h1cw[63*256 + tid]);
          v4[tid] = lrel(&dc1i[tid]);
          v5[tid] = lrel(&h2cw[63*256 + tid]);
          v6[tid] = lrel(&dc2i[tid]);
          v2[tid] = lrel(&h2cw[0*256 + tid]);
        }
        __syncthreads();
        dec_cell();
      }
      // scores: 16 lanes per t
      { int t = tid >> 4, r = tid & 15;
        float a = 0.f;
        for (int j = r; j < HH; j += 16) a += vv[j] * tanhf(big1[t*256 + j] + v1[j]);
        a += __shfl_xor(a, 8, 16);
        a += __shfl_xor(a, 4, 16);
        a += __shfl_xor(a, 2, 16);
        a += __shfl_xor(a, 1, 16);
        if (r == 0) scr[t] = msk[t] ? -3.0e38f : a; }
      __syncthreads();
      if (tid < SS){
        float sv = scr[tid];
        float m = sv; int mi = tid;
#pragma unroll
        for (int o = 32; o >= 1; o >>= 1){
          float ov = __shfl_xor(m, o, 64);
          int oi = __shfl_xor(mi, o, 64);
          if (ov > m || (ov == m && oi < mi)){ m = ov; mi = oi; }
        }
        float e = expf(sv - m);
        float ssum = e;
#pragma unroll
        for (int o = 32; o >= 1; o >>= 1) ssum += __shfl_xor(ssum, o, 64);
        out[((size_t)b*SS + p)*SS + tid] = e / ssum;
        if (tid == 0){
          msk[mi] = 1;
          out[(size_t)BB*SS*SS + (size_t)b*SS + p] = (float)mi;
          ibc[1] = mi;
        }
      }
      __syncthreads();
      int idx = ibc[1];
      lastidx = idx;
      if (p < SS-1){
        if (tid < 256){
          v2[tid] = lrel(&h2cw[idx*256 + tid]);   // dins (read BEFORE publish)
          float e = tanhf(big0[idx*256 + tid] + W_emb[tid*8 + 7]);
          srel(&embw[tid], e);
        }
        drain_vm();
        __syncthreads();
        if (tid == 0) fst(&flg[3], ((unsigned)(p+1) << 8) | (unsigned)idx);
      }
    }
  }
}

extern "C" void kernel_launch(void* const* d_in, const int* in_sizes, int n_in,
                              void* d_out, int out_size, void* d_ws, size_t ws_size,
                              hipStream_t stream) {
  const float* inputs = (const float*)d_in[0];
  const float* W_emb  = (const float*)d_in[1];
  const float* b_emb  = (const float*)d_in[2];
  const float* e_Wih0 = (const float*)d_in[3];
  const float* e_Whh0 = (const float*)d_in[4];
  const float* e_b0   = (const float*)d_in[5];
  const float* e_Wih1 = (const float*)d_in[6];
  const float* e_Whh1 = (const float*)d_in[7];
  const float* e_b1   = (const float*)d_in[8];
  const float* d_Wih0 = (const float*)d_in[9];
  const float* d_Whh0 = (const float*)d_in[10];
  const float* d_b0   = (const float*)d_in[11];
  const float* d_Wih1 = (const float*)d_in[12];
  const float* d_Whh1 = (const float*)d_in[13];
  const float* d_b1   = (const float*)d_in[14];
  const float* W1     = (const float*)d_in[15];
  const float* W2     = (const float*)d_in[16];
  const float* v      = (const float*)d_in[17];
  float* ws  = (float*)d_ws;
  float* out = (float*)d_out;

  zflags_k<<<dim3(1), dim3(512), 0, stream>>>(ws);
  pack_transpose_k<<<dim3(16, 4, 8), dim3(256), 0, stream>>>(
      e_Wih0, e_Whh0, e_Wih1, e_Whh1, d_Wih0, d_Whh0, d_Wih1, d_Whh1, ws);
  transpose256_k<<<dim3(8, 8, 2), dim3(256), 0, stream>>>(W1, W2, ws);
  ptrnet_k<<<dim3(BB*4), dim3(NT), 0, stream>>>(
      inputs, W_emb, b_emb, e_b0, e_b1, d_b0, d_b1, v, ws, out);
}